// Round 4
// baseline (266.094 us; speedup 1.0000x reference)
//
#include <hip/hip_runtime.h>
#include <hip/hip_bf16.h>

#define S_LEN 4096
#define D_EMB 768
#define NH    12
#define HD    64
#define DQKV  2304
#define DFF   3072

typedef __attribute__((ext_vector_type(4))) short short4v;
typedef __attribute__((ext_vector_type(8))) short short8v;
typedef __attribute__((ext_vector_type(4))) float float4v;

static __device__ __forceinline__ float4v mfma16(short4v a, short4v b, float4v c) {
  return __builtin_amdgcn_mfma_f32_16x16x16bf16_1k(a, b, c, 0, 0, 0);
}

static __device__ __forceinline__ short bf16bits(float f) {
  __hip_bfloat16 h = __float2bfloat16(f);
  return *reinterpret_cast<short*>(&h);
}

// async global -> LDS, 16B per lane. LDS dest must be wave-uniform base + lane*16.
static __device__ __forceinline__ void gload16(const __hip_bfloat16* g, __hip_bfloat16* l) {
  __builtin_amdgcn_global_load_lds((const __attribute__((address_space(1))) void*)g,
                                   (__attribute__((address_space(3))) void*)l, 16, 0, 0);
}

// ---------------- LayerNorm: fp32 in -> bf16 out, one block per row ----------------
__global__ __launch_bounds__(256) void ln_kernel(const float* __restrict__ x,
    const float* __restrict__ g, const float* __restrict__ b,
    __hip_bfloat16* __restrict__ out)
{
  int row = blockIdx.x;
  int tid = threadIdx.x;
  const float* xr = x + (size_t)row * D_EMB;
  float v0 = xr[tid], v1 = xr[tid + 256], v2 = xr[tid + 512];
  float s  = v0 + v1 + v2;
  float sq = v0 * v0 + v1 * v1 + v2 * v2;
  #pragma unroll
  for (int off = 32; off >= 1; off >>= 1) {
    s  += __shfl_xor(s, off);
    sq += __shfl_xor(sq, off);
  }
  __shared__ float ss[4], ssq[4];
  if ((tid & 63) == 0) { ss[tid >> 6] = s; ssq[tid >> 6] = sq; }
  __syncthreads();
  s  = ss[0] + ss[1] + ss[2] + ss[3];
  sq = ssq[0] + ssq[1] + ssq[2] + ssq[3];
  float mean = s * (1.0f / D_EMB);
  float var  = sq * (1.0f / D_EMB) - mean * mean;
  float rstd = rsqrtf(var + 1e-5f);
  __hip_bfloat16* orow = out + (size_t)row * D_EMB;
  orow[tid]       = __float2bfloat16((v0 - mean) * rstd * g[tid]       + b[tid]);
  orow[tid + 256] = __float2bfloat16((v1 - mean) * rstd * g[tid + 256] + b[tid + 256]);
  orow[tid + 512] = __float2bfloat16((v2 - mean) * rstd * g[tid + 512] + b[tid + 512]);
}

// ---------------- fp32 [K][N] -> bf16 [N][K] tiled transpose ----------------
__global__ __launch_bounds__(256) void transpose_bf16_kernel(const float* __restrict__ in,
    __hip_bfloat16* __restrict__ out, int K, int N)
{
  __shared__ float t[32][33];
  int nb = N >> 5;
  int bn = blockIdx.x % nb, bk = blockIdx.x / nb;
  int tx = threadIdx.x & 31, ty = threadIdx.x >> 5;
  #pragma unroll
  for (int i = 0; i < 4; i++)
    t[ty + 8 * i][tx] = in[(size_t)(bk * 32 + ty + 8 * i) * N + bn * 32 + tx];
  __syncthreads();
  #pragma unroll
  for (int i = 0; i < 4; i++)
    out[(size_t)(bn * 32 + ty + 8 * i) * K + bk * 32 + tx] = __float2bfloat16(t[tx][ty + 8 * i]);
}

// ---------------- GEMM (m97 structure): C = A[M,K] * Bt[N,K]^T + bias ----------------
template<int EPI>
__global__ __launch_bounds__(256) void gemm_kernel(
    const __hip_bfloat16* __restrict__ A,
    const __hip_bfloat16* __restrict__ Bt,
    const float* __restrict__ bias,
    const float* __restrict__ resid,
    void* __restrict__ Cout,
    int M, int N, int K)
{
  __shared__ __hip_bfloat16 Asm[128 * 64];
  __shared__ __hip_bfloat16 Bsm[128 * 64];
  int nb = N >> 7;
  int bx = blockIdx.x % nb, by = blockIdx.x / nb;
  int m0 = by << 7, n0 = bx << 7;
  int tid = threadIdx.x;
  int lane = tid & 63, lg = lane >> 4, li = lane & 15;
  int w = tid >> 6, wr = w >> 1, wc = w & 1;

  int sr  = tid >> 3;
  int scn = (tid & 7) ^ (sr & 7);
  const __hip_bfloat16* aSrc = A  + (size_t)(m0 + sr) * K + scn * 8;
  const __hip_bfloat16* bSrc = Bt + (size_t)(n0 + sr) * K + scn * 8;
  __hip_bfloat16* aDst = Asm + tid * 8;
  __hip_bfloat16* bDst = Bsm + tid * 8;
  const size_t rowStep = (size_t)32 * K;

  float4v acc[4][4];
  #pragma unroll
  for (int i = 0; i < 4; i++)
    #pragma unroll
    for (int j = 0; j < 4; j++) {
      float4v z = {0.f, 0.f, 0.f, 0.f};
      acc[i][j] = z;
    }

  int sw = li & 7;

  for (int kt = 0; kt < K; kt += 64) {
    #pragma unroll
    for (int i = 0; i < 4; i++) {
      gload16(aSrc + i * rowStep, aDst + i * 2048);
      gload16(bSrc + i * rowStep, bDst + i * 2048);
    }
    aSrc += 64; bSrc += 64;
    __syncthreads();
    #pragma unroll
    for (int kk = 0; kk < 2; kk++) {
      short8v af[4], bf[4];
      #pragma unroll
      for (int f = 0; f < 4; f++) {
        int ar = wr * 64 + f * 16 + li;
        int br = wc * 64 + f * 16 + li;
        int ch = ((kk << 2) | lg) ^ sw;
        af[f] = *(const short8v*)(Asm + ar * 64 + ch * 8);
        bf[f] = *(const short8v*)(Bsm + br * 64 + ch * 8);
      }
      #pragma unroll
      for (int fr = 0; fr < 4; fr++)
        #pragma unroll
        for (int fc = 0; fc < 4; fc++)
          acc[fr][fc] = __builtin_amdgcn_mfma_f32_16x16x32_bf16(af[fr], bf[fc], acc[fr][fc], 0, 0, 0);
    }
    __syncthreads();
  }

  #pragma unroll
  for (int fr = 0; fr < 4; fr++) {
    int row = m0 + wr * 64 + fr * 16 + lg * 4;
    #pragma unroll
    for (int fc = 0; fc < 4; fc++) {
      int col = n0 + wc * 64 + fc * 16 + li;
      float bv = bias[col];
      #pragma unroll
      for (int r = 0; r < 4; r++) {
        float v = acc[fr][fc][r] + bv;
        size_t idx = (size_t)(row + r) * N + col;
        if (EPI == 1) {
          v = 0.5f * v * (1.0f + erff(v * 0.70710678118654752f));
          ((__hip_bfloat16*)Cout)[idx] = __float2bfloat16(v);
        } else if (EPI == 2) {
          ((float*)Cout)[idx] = v + resid[idx];
        } else {
          ((__hip_bfloat16*)Cout)[idx] = __float2bfloat16(v);
        }
      }
    }
  }
}

// ---------------- causal flash attention v3 ----------------
// Swapped-operand (S^T = K*Q^T), in-register P, double-buffered K/V LDS,
// K staged via global_load_lds with chunk-swizzle, 16x16x32 QK^T, defer-max.
__global__ __launch_bounds__(256) void attn_kernel(const __hip_bfloat16* __restrict__ kqv,
                                                   __hip_bfloat16* __restrict__ y)
{
  __shared__ __hip_bfloat16 Ksm[2][64 * 64];   // [kv][d] linear, swizzled content
  __shared__ __hip_bfloat16 Vtsm[2][64][66];   // [d][kv]

  // XCD-aware bijective remap: 768 blocks = 8 XCDs x 96
  int bid = blockIdx.x;
  int g = (bid >> 3) + (bid & 7) * 96;
  int h  = g >> 6;
  int qb = 63 - (g & 63);           // heavy blocks first within each XCD slice
  int tid = threadIdx.x;
  int w = tid >> 6, lane = tid & 63, lg = lane >> 4, li = lane & 15;

  // Q as B-operand of 16x16x32: lane li = q-col, k(d) = kk*32 + 8*lg + j
  short8v q8[2];
  {
    const __hip_bfloat16* qp = kqv + (size_t)(qb * 64 + w * 16 + li) * DQKV + D_EMB + h * HD + 8 * lg;
    q8[0] = *(const short8v*)(qp);
    q8[1] = *(const short8v*)(qp + 32);
  }

  float m = -1e30f, lsum = 0.f;
  float4v o[4];
  #pragma unroll
  for (int fc = 0; fc < 4; fc++) { float4v z = {0.f,0.f,0.f,0.f}; o[fc] = z; }

  // K staging roles (global_load_lds, 2 issues x 256 thr x 16B)
  int ksr  = tid >> 3;                    // 0..31 (+32 on issue 1)
  int kscn = (tid & 7) ^ (ksr & 7);       // swizzled source chunk
  const __hip_bfloat16* kSrc0 = kqv + h * HD + (size_t)ksr * DQKV + kscn * 8;
  // V staging roles (register path, transposed write)
  int vr = (tid >> 3) << 1, vc = (tid & 7) << 3;
  const __hip_bfloat16* vSrc0 = kqv + 2 * D_EMB + h * HD + (size_t)vr * DQKV + vc;

  const size_t kRowStep = (size_t)32 * DQKV;
  const size_t tileStep = (size_t)64 * DQKV;

  short8v vA, vB;
  // ---- prologue: stage tile 0 into buffer 0 ----
  gload16(kSrc0,            &Ksm[0][tid * 8]);
  gload16(kSrc0 + kRowStep, &Ksm[0][tid * 8 + 2048]);
  vA = *(const short8v*)(vSrc0);
  vB = *(const short8v*)(vSrc0 + DQKV);
  #pragma unroll
  for (int j = 0; j < 8; j++) {
    unsigned int pk = (unsigned int)(unsigned short)vA[j]
                    | ((unsigned int)(unsigned short)vB[j] << 16);
    *reinterpret_cast<unsigned int*>(&Vtsm[0][vc + j][vr]) = pk;
  }
  __syncthreads();

  int sw = li & 7;
  for (int kb = 0; kb <= qb; kb++) {
    int p = kb & 1;
    // prefetch tile kb+1 into buffer p^1
    if (kb < qb) {
      const __hip_bfloat16* ks = kSrc0 + (size_t)(kb + 1) * tileStep;
      gload16(ks,            &Ksm[p ^ 1][tid * 8]);
      gload16(ks + kRowStep, &Ksm[p ^ 1][tid * 8 + 2048]);
      const __hip_bfloat16* vs = vSrc0 + (size_t)(kb + 1) * tileStep;
      vA = *(const short8v*)(vs);
      vB = *(const short8v*)(vs + DQKV);
    }

    // S^T = K * Q^T : s[fc] covers kv = fc*16 + 4*lg + r, q = li
    float4v s[4];
    #pragma unroll
    for (int fc = 0; fc < 4; fc++) { float4v z = {0.f,0.f,0.f,0.f}; s[fc] = z; }
    #pragma unroll
    for (int kk = 0; kk < 2; kk++) {
      #pragma unroll
      for (int fc = 0; fc < 4; fc++) {
        int ch = ((kk << 2) | lg) ^ sw;
        short8v kf = *(const short8v*)(&Ksm[p][(fc * 16 + li) * 64 + ch * 8]);
        s[fc] = __builtin_amdgcn_mfma_f32_16x16x32_bf16(kf, q8[kk], s[fc], 0, 0, 0);
      }
    }

    // online softmax with defer-max (THR=8)
    bool diag = (kb == qb);
    float pmax = -1e30f;
    #pragma unroll
    for (int fc = 0; fc < 4; fc++) {
      #pragma unroll
      for (int r = 0; r < 4; r++) {
        float v = s[fc][r] * 0.125f;
        if (diag && (fc * 16 + 4 * lg + r) > (w * 16 + li)) v = -1e30f;
        s[fc][r] = v;
        pmax = fmaxf(pmax, v);
      }
    }
    pmax = fmaxf(pmax, __shfl_xor(pmax, 16));
    pmax = fmaxf(pmax, __shfl_xor(pmax, 32));
    if (!__all(pmax - m <= 8.0f)) {
      float mn = fmaxf(m, pmax);
      float alpha = __expf(m - mn);
      lsum *= alpha;
      #pragma unroll
      for (int fc = 0; fc < 4; fc++) {
        #pragma unroll
        for (int r = 0; r < 4; r++) o[fc][r] *= alpha;
      }
      m = mn;
    }
    float rs = 0.f;
    #pragma unroll
    for (int fc = 0; fc < 4; fc++) {
      #pragma unroll
      for (int r = 0; r < 4; r++) {
        float pv = __expf(s[fc][r] - m);
        s[fc][r] = pv;
        rs += pv;
      }
    }
    rs += __shfl_xor(rs, 16);
    rs += __shfl_xor(rs, 32);
    lsum += rs;

    // P^T fragments (B-operand of 16x16x16) straight from registers
    short4v pb[4];
    #pragma unroll
    for (int kk = 0; kk < 4; kk++) {
      short4v t;
      #pragma unroll
      for (int r = 0; r < 4; r++) t[r] = bf16bits(s[kk][r]);
      pb[kk] = t;
    }

    // O^T += V^T * P^T
    #pragma unroll
    for (int kk = 0; kk < 4; kk++) {
      #pragma unroll
      for (int fc = 0; fc < 4; fc++) {
        short4v vf = *(const short4v*)(&Vtsm[p][fc * 16 + li][kk * 16 + 4 * lg]);
        o[fc] = mfma16(vf, pb[kk], o[fc]);
      }
    }

    // late V-transpose write for tile kb+1 into buffer p^1
    if (kb < qb) {
      #pragma unroll
      for (int j = 0; j < 8; j++) {
        unsigned int pk = (unsigned int)(unsigned short)vA[j]
                        | ((unsigned int)(unsigned short)vB[j] << 16);
        *reinterpret_cast<unsigned int*>(&Vtsm[p ^ 1][vc + j][vr]) = pk;
      }
    }
    __syncthreads();
  }

  float inv = 1.0f / lsum;
  int qrow = qb * 64 + w * 16 + li;
  #pragma unroll
  for (int fc = 0; fc < 4; fc++) {
    short4v ov;
    #pragma unroll
    for (int r = 0; r < 4; r++) ov[r] = bf16bits(o[fc][r] * inv);
    *reinterpret_cast<short4v*>(y + (size_t)qrow * D_EMB + h * HD + fc * 16 + 4 * lg) = ov;
  }
}

// ---------------- launch ----------------
extern "C" void kernel_launch(void* const* d_in, const int* in_sizes, int n_in,
                              void* d_out, int out_size, void* d_ws, size_t ws_size,
                              hipStream_t stream)
{
  const float* x      = (const float*)d_in[0];
  const float* w_qkv  = (const float*)d_in[1];
  const float* b_qkv  = (const float*)d_in[2];
  const float* w_proj = (const float*)d_in[3];
  const float* b_proj = (const float*)d_in[4];
  const float* w_fc1  = (const float*)d_in[5];
  const float* b_fc1  = (const float*)d_in[6];
  const float* w_fc2  = (const float*)d_in[7];
  const float* b_fc2  = (const float*)d_in[8];
  const float* ln1_g  = (const float*)d_in[9];
  const float* ln1_b  = (const float*)d_in[10];
  const float* ln2_g  = (const float*)d_in[11];
  const float* ln2_b  = (const float*)d_in[12];

  char* ws = (char*)d_ws;
  size_t off = 0;
  __hip_bfloat16* wqkvT = (__hip_bfloat16*)(ws + off); off += (size_t)DQKV * D_EMB * 2;
  __hip_bfloat16* wprojT= (__hip_bfloat16*)(ws + off); off += (size_t)D_EMB * D_EMB * 2;
  __hip_bfloat16* wfc1T = (__hip_bfloat16*)(ws + off); off += (size_t)DFF * D_EMB * 2;
  __hip_bfloat16* wfc2T = (__hip_bfloat16*)(ws + off); off += (size_t)D_EMB * DFF * 2;
  __hip_bfloat16* lnbuf = (__hip_bfloat16*)(ws + off); off += (size_t)S_LEN * D_EMB * 2;
  __hip_bfloat16* kqv   = (__hip_bfloat16*)(ws + off);
  __hip_bfloat16* hbuf  = kqv;                         off += (size_t)S_LEN * DQKV * 2;
  __hip_bfloat16* ybuf  = (__hip_bfloat16*)(ws + off); off += (size_t)S_LEN * D_EMB * 2;
  float*          x1    = (float*)(ws + off);          off += (size_t)S_LEN * D_EMB * 4;
  (void)ws_size; (void)in_sizes; (void)n_in; (void)out_size;

  transpose_bf16_kernel<<<dim3((DQKV/32)*(D_EMB/32)), dim3(256), 0, stream>>>(w_qkv,  wqkvT, D_EMB, DQKV);
  transpose_bf16_kernel<<<dim3((D_EMB/32)*(D_EMB/32)), dim3(256), 0, stream>>>(w_proj, wprojT, D_EMB, D_EMB);
  transpose_bf16_kernel<<<dim3((DFF/32)*(D_EMB/32)),   dim3(256), 0, stream>>>(w_fc1,  wfc1T, D_EMB, DFF);
  transpose_bf16_kernel<<<dim3((D_EMB/32)*(DFF/32)),   dim3(256), 0, stream>>>(w_fc2,  wfc2T, DFF, D_EMB);

  ln_kernel<<<dim3(S_LEN), dim3(256), 0, stream>>>(x, ln1_g, ln1_b, lnbuf);
  gemm_kernel<0><<<dim3((DQKV/128)*(S_LEN/128)), dim3(256), 0, stream>>>(
      lnbuf, wqkvT, b_qkv, nullptr, kqv, S_LEN, DQKV, D_EMB);
  attn_kernel<<<dim3(NH * (S_LEN/64)), dim3(256), 0, stream>>>(kqv, ybuf);
  gemm_kernel<2><<<dim3((D_EMB/128)*(S_LEN/128)), dim3(256), 0, stream>>>(
      ybuf, wprojT, b_proj, x, x1, S_LEN, D_EMB, D_EMB);
  ln_kernel<<<dim3(S_LEN), dim3(256), 0, stream>>>(x1, ln2_g, ln2_b, lnbuf);
  gemm_kernel<1><<<dim3((DFF/128)*(S_LEN/128)), dim3(256), 0, stream>>>(
      lnbuf, wfc1T, b_fc1, nullptr, hbuf, S_LEN, DFF, D_EMB);
  gemm_kernel<2><<<dim3((D_EMB/128)*(S_LEN/128)), dim3(256), 0, stream>>>(
      hbuf, wfc2T, b_fc2, x1, (float*)d_out, S_LEN, D_EMB, DFF);
}